// Round 1
// baseline (1192.980 us; speedup 1.0000x reference)
//
#include <hip/hip_runtime.h>
#include <math.h>

#define DM    1024
#define NH    16
#define DK    64
#define SLEN  2048
#define NB    2
#define MROWS (NB*SLEN)   // 4096

// word-index swizzle inside a [64][64] fp32 tile: 16B chunks XORed by (row>>2)&7
__device__ __forceinline__ int swz64(int row, int col) {
    int ch = (col >> 2) ^ ((row >> 2) & 7);
    return (row << 6) + (ch << 2) + (col & 3);
}

// ---------------- GEMM: out = A[M x DM] @ W[DM x DM] + bias ----------------
// reshape=0: out[m][n] row-major [MROWS][DM]
// reshape=1: out[((b*NH+h)*SLEN+s)*DK + d]   (head-split layout for attention)
__global__ __launch_bounds__(256) void gemm128(
    const float* __restrict__ A, const float* __restrict__ W,
    const float* __restrict__ bias, float* __restrict__ out, int reshape)
{
    __shared__ float As[32 * 132];   // A tile transposed: As[k][m], pad 132
    __shared__ float Bs[32 * 128];   // W tile: Bs[k][n]
    const int tid = threadIdx.x;
    const int bm = blockIdx.x << 7;
    const int bn = blockIdx.y << 7;
    const int ty = tid >> 4;         // 0..15
    const int tx = tid & 15;         // 0..15

    float acc[8][8];
#pragma unroll
    for (int i = 0; i < 8; ++i)
#pragma unroll
        for (int j = 0; j < 8; ++j) acc[i][j] = 0.f;

    const int ar = tid >> 3;         // 0..31 (A tile row within pass)
    const int ak = (tid & 7) << 2;   // 0..28 (k offset)
    const int wr = tid >> 5;         // 0..7  (W tile k-row within pass)
    const int wc = (tid & 31) << 2;  // 0..124

    for (int k0 = 0; k0 < DM; k0 += 32) {
        __syncthreads();
#pragma unroll
        for (int u = 0; u < 4; ++u) {
            float4 av = *(const float4*)&A[(size_t)(bm + ar + (u << 5)) * DM + k0 + ak];
            As[(ak + 0) * 132 + ar + (u << 5)] = av.x;
            As[(ak + 1) * 132 + ar + (u << 5)] = av.y;
            As[(ak + 2) * 132 + ar + (u << 5)] = av.z;
            As[(ak + 3) * 132 + ar + (u << 5)] = av.w;
            float4 wv = *(const float4*)&W[(size_t)(k0 + wr + (u << 3)) * DM + bn + wc];
            *(float4*)&Bs[(wr + (u << 3)) * 128 + wc] = wv;
        }
        __syncthreads();
#pragma unroll
        for (int kk = 0; kk < 32; ++kk) {
            float4 a0 = *(const float4*)&As[kk * 132 + (ty << 2)];
            float4 a1 = *(const float4*)&As[kk * 132 + (ty << 2) + 64];
            float4 b0 = *(const float4*)&Bs[kk * 128 + (tx << 2)];
            float4 b1 = *(const float4*)&Bs[kk * 128 + (tx << 2) + 64];
            float av8[8] = {a0.x, a0.y, a0.z, a0.w, a1.x, a1.y, a1.z, a1.w};
            float bv8[8] = {b0.x, b0.y, b0.z, b0.w, b1.x, b1.y, b1.z, b1.w};
#pragma unroll
            for (int i = 0; i < 8; ++i)
#pragma unroll
                for (int j = 0; j < 8; ++j)
                    acc[i][j] = fmaf(av8[i], bv8[j], acc[i][j]);
        }
    }

    float4 bb0 = *(const float4*)&bias[bn + (tx << 2)];
    float4 bb1 = *(const float4*)&bias[bn + (tx << 2) + 64];
    float bv8[8] = {bb0.x, bb0.y, bb0.z, bb0.w, bb1.x, bb1.y, bb1.z, bb1.w};
#pragma unroll
    for (int i = 0; i < 8; ++i) {
        int m = bm + (ty << 2) + (i & 3) + ((i >> 2) << 6);
        float4 o0 = make_float4(acc[i][0] + bv8[0], acc[i][1] + bv8[1],
                                acc[i][2] + bv8[2], acc[i][3] + bv8[3]);
        float4 o1 = make_float4(acc[i][4] + bv8[4], acc[i][5] + bv8[5],
                                acc[i][6] + bv8[6], acc[i][7] + bv8[7]);
        if (reshape == 0) {
            *(float4*)&out[(size_t)m * DM + bn + (tx << 2)]      = o0;
            *(float4*)&out[(size_t)m * DM + bn + (tx << 2) + 64] = o1;
        } else {
            int b_ = m >> 11, s_ = m & (SLEN - 1);
            int n0 = bn + (tx << 2);
            int h0 = n0 >> 6, d0 = n0 & 63;
            int h1 = (n0 + 64) >> 6;
            size_t base0 = ((size_t)(b_ * NH + h0) * SLEN + s_) * DK + d0;
            size_t base1 = ((size_t)(b_ * NH + h1) * SLEN + s_) * DK + d0;
            *(float4*)&out[base0] = o0;
            *(float4*)&out[base1] = o1;
        }
    }
}

// ---------------- flash attention (fp32), one (b,h) x 64-row Q tile per block ----
// q/k/v: [B*NH][SLEN][DK]; out: [B][SLEN][DM] (heads re-interleaved)
__global__ __launch_bounds__(256) void attn64(
    const float* __restrict__ Qg, const float* __restrict__ Kg,
    const float* __restrict__ Vg, float* __restrict__ outg)
{
    __shared__ float Qs[64 * 64];
    __shared__ float Ks[64 * 64];
    __shared__ float Vs[64 * 64];
    __shared__ float Ps[64 * 64];
    const int tid = threadIdx.x;
    const int bh = blockIdx.y;
    const int q0 = blockIdx.x << 6;
    const float* Qp = Qg + (size_t)bh * SLEN * DK;
    const float* Kp = Kg + (size_t)bh * SLEN * DK;
    const float* Vp = Vg + (size_t)bh * SLEN * DK;

    const int lrow = tid >> 4;         // 0..15
    const int lcol = (tid & 15) << 2;  // 0..60

#pragma unroll
    for (int u = 0; u < 4; ++u) {
        int r = lrow + (u << 4);
        *(float4*)&Qs[swz64(r, lcol)] =
            *(const float4*)&Qp[(size_t)(q0 + r) * DK + lcol];
    }

    const int ty = tid >> 4;   // row group 0..15
    const int tx = tid & 15;   // col group 0..15
    const int r0 = ty << 2;
    const int c0 = tx << 2;

    float m_i[4], l_i[4], O[4][4];
#pragma unroll
    for (int i = 0; i < 4; ++i) {
        m_i[i] = -1e30f; l_i[i] = 0.f;
#pragma unroll
        for (int j = 0; j < 4; ++j) O[i][j] = 0.f;
    }

    for (int t = 0; t < SLEN / 64; ++t) {
        __syncthreads();   // previous tile fully consumed
        const int kb = t << 6;
#pragma unroll
        for (int u = 0; u < 4; ++u) {
            int r = lrow + (u << 4);
            *(float4*)&Ks[swz64(r, lcol)] =
                *(const float4*)&Kp[(size_t)(kb + r) * DK + lcol];
            *(float4*)&Vs[swz64(r, lcol)] =
                *(const float4*)&Vp[(size_t)(kb + r) * DK + lcol];
        }
        __syncthreads();

        // S = (Q K^T) * 1/sqrt(DK)
        float s[4][4];
#pragma unroll
        for (int i = 0; i < 4; ++i)
#pragma unroll
            for (int j = 0; j < 4; ++j) s[i][j] = 0.f;
#pragma unroll
        for (int d = 0; d < 64; d += 4) {
            float4 q4[4], k4[4];
#pragma unroll
            for (int i = 0; i < 4; ++i) q4[i] = *(const float4*)&Qs[swz64(r0 + i, d)];
#pragma unroll
            for (int j = 0; j < 4; ++j) k4[j] = *(const float4*)&Ks[swz64(c0 + j, d)];
#pragma unroll
            for (int i = 0; i < 4; ++i) {
                const float* qq = (const float*)&q4[i];
#pragma unroll
                for (int j = 0; j < 4; ++j) {
                    const float* kv = (const float*)&k4[j];
                    s[i][j] = fmaf(qq[0], kv[0], s[i][j]);
                    s[i][j] = fmaf(qq[1], kv[1], s[i][j]);
                    s[i][j] = fmaf(qq[2], kv[2], s[i][j]);
                    s[i][j] = fmaf(qq[3], kv[3], s[i][j]);
                }
            }
        }
#pragma unroll
        for (int i = 0; i < 4; ++i)
#pragma unroll
            for (int j = 0; j < 4; ++j) s[i][j] *= 0.125f;

        // online softmax (per-row state replicated across the 16-lane row group)
        float p[4][4];
#pragma unroll
        for (int i = 0; i < 4; ++i) {
            float mx = fmaxf(fmaxf(s[i][0], s[i][1]), fmaxf(s[i][2], s[i][3]));
            mx = fmaxf(mx, __shfl_xor(mx, 1));
            mx = fmaxf(mx, __shfl_xor(mx, 2));
            mx = fmaxf(mx, __shfl_xor(mx, 4));
            mx = fmaxf(mx, __shfl_xor(mx, 8));
            float mn = fmaxf(m_i[i], mx);
            float al = __expf(m_i[i] - mn);
            m_i[i] = mn;
            float rs = 0.f;
#pragma unroll
            for (int j = 0; j < 4; ++j) {
                p[i][j] = __expf(s[i][j] - mn);
                rs += p[i][j];
            }
            rs += __shfl_xor(rs, 1);
            rs += __shfl_xor(rs, 2);
            rs += __shfl_xor(rs, 4);
            rs += __shfl_xor(rs, 8);
            l_i[i] = l_i[i] * al + rs;
#pragma unroll
            for (int j = 0; j < 4; ++j) O[i][j] *= al;
        }

        // publish P tile
#pragma unroll
        for (int i = 0; i < 4; ++i)
            *(float4*)&Ps[swz64(r0 + i, c0)] =
                make_float4(p[i][0], p[i][1], p[i][2], p[i][3]);
        __syncthreads();

        // O += P * V
#pragma unroll
        for (int kk = 0; kk < 64; kk += 4) {
            float4 p4[4], v4[4];
#pragma unroll
            for (int i = 0; i < 4; ++i) p4[i] = *(const float4*)&Ps[swz64(r0 + i, kk)];
#pragma unroll
            for (int u = 0; u < 4; ++u) v4[u] = *(const float4*)&Vs[swz64(kk + u, c0)];
#pragma unroll
            for (int i = 0; i < 4; ++i) {
                const float* pp = (const float*)&p4[i];
#pragma unroll
                for (int u = 0; u < 4; ++u) {
                    const float* vv = (const float*)&v4[u];
#pragma unroll
                    for (int j = 0; j < 4; ++j)
                        O[i][j] = fmaf(pp[u], vv[j], O[i][j]);
                }
            }
        }
    }

    // epilogue: normalize and write [B][S][DM] with heads interleaved
    const int b_ = bh >> 4, h_ = bh & 15;
#pragma unroll
    for (int i = 0; i < 4; ++i) {
        float inv = 1.f / l_i[i];
        int srow = q0 + r0 + i;
        *(float4*)&outg[((size_t)(b_ * SLEN + srow)) * DM + (h_ << 6) + c0] =
            make_float4(O[i][0] * inv, O[i][1] * inv, O[i][2] * inv, O[i][3] * inv);
    }
}

extern "C" void kernel_launch(void* const* d_in, const int* in_sizes, int n_in,
                              void* d_out, int out_size, void* d_ws, size_t ws_size,
                              hipStream_t stream) {
    const float* x  = (const float*)d_in[0];
    const float* Wq = (const float*)d_in[1];
    const float* bq = (const float*)d_in[2];
    const float* Wk = (const float*)d_in[3];
    const float* bk = (const float*)d_in[4];
    const float* Wv = (const float*)d_in[5];
    const float* bv = (const float*)d_in[6];
    const float* Wo = (const float*)d_in[7];
    const float* bo = (const float*)d_in[8];
    float* out = (float*)d_out;
    float* ws  = (float*)d_ws;

    const size_t buf = (size_t)MROWS * DM;   // 4M floats per buffer
    if (ws_size < 4 * buf * sizeof(float)) return;  // need 64MB scratch

    float* qw = ws;
    float* kw = ws + buf;
    float* vw = ws + 2 * buf;
    float* aw = ws + 3 * buf;

    dim3 gg(MROWS / 128, DM / 128), gb(256);
    hipLaunchKernelGGL(gemm128, gg, gb, 0, stream, x, Wq, bq, qw, 1);
    hipLaunchKernelGGL(gemm128, gg, gb, 0, stream, x, Wk, bk, kw, 1);
    hipLaunchKernelGGL(gemm128, gg, gb, 0, stream, x, Wv, bv, vw, 1);
    hipLaunchKernelGGL(attn64, dim3(SLEN / 64, NB * NH), gb, 0, stream, qw, kw, vw, aw);
    hipLaunchKernelGGL(gemm128, gg, gb, 0, stream, aw, Wo, bo, out, 0);
}

// Round 2
// 253.276 us; speedup vs baseline: 4.7102x; 4.7102x over previous
//
#include <hip/hip_runtime.h>
#include <math.h>

#define DM    1024
#define NH    16
#define DK    64
#define SLEN  2048
#define NB    2
#define MROWS (NB*SLEN)   // 4096

typedef unsigned short u16;
typedef short  s16x8 __attribute__((ext_vector_type(8)));
typedef _Float16 f16x8 __attribute__((ext_vector_type(8)));
typedef float  f32x4 __attribute__((ext_vector_type(4)));

#define MFMA_BF16(a,b,c) __builtin_amdgcn_mfma_f32_16x16x32_bf16(a,b,c,0,0,0)
#define MFMA_F16(a,b,c)  __builtin_amdgcn_mfma_f32_16x16x32_f16(a,b,c,0,0,0)

__device__ __forceinline__ void gload16(const void* g, void* l) {
    __builtin_amdgcn_global_load_lds((const __attribute__((address_space(1))) void*)g,
                                     (__attribute__((address_space(3))) void*)l, 16, 0, 0);
}

__device__ __forceinline__ u16 f2bf(float x) {   // RNE float->bf16 bits
    union { float f; unsigned int u; } v; v.f = x;
    unsigned int r = v.u + 0x7fffu + ((v.u >> 16) & 1u);
    return (u16)(r >> 16);
}
__device__ __forceinline__ float bf2f(u16 u) {
    union { unsigned int u; float f; } v; v.u = ((unsigned int)u) << 16;
    return v.f;
}

// ---------- split x (f32) -> hi/lo bf16, same layout ----------
__global__ __launch_bounds__(256) void cvt_x(const float* __restrict__ in,
                                             u16* __restrict__ h, u16* __restrict__ l) {
    int i = (blockIdx.x * 256 + threadIdx.x) * 4;
    float4 v = *(const float4*)&in[i];
    float vv[4] = {v.x, v.y, v.z, v.w};
    ushort4 hv, lv;
    u16* hp = (u16*)&hv; u16* lp = (u16*)&lv;
#pragma unroll
    for (int j = 0; j < 4; ++j) {
        u16 hb = f2bf(vv[j]);
        hp[j] = hb;
        lp[j] = f2bf(vv[j] - bf2f(hb));
    }
    *(ushort4*)&h[i] = hv;
    *(ushort4*)&l[i] = lv;
}

// ---------- split + transpose W (f32 [k][n]) -> Wt hi/lo bf16 [n][k] ----------
__global__ __launch_bounds__(256) void cvt_wt(const float* __restrict__ W,
                                              u16* __restrict__ th, u16* __restrict__ tl) {
    __shared__ u16 lh[64][72], ll[64][72];
    int k0 = blockIdx.x * 64, n0 = blockIdx.y * 64;
    int t = threadIdx.x;
    int kr = t >> 4, c4 = (t & 15) * 4;
#pragma unroll
    for (int u = 0; u < 4; ++u) {
        int k = kr + u * 16;
        float4 v = *(const float4*)&W[(size_t)(k0 + k) * DM + n0 + c4];
        float vv[4] = {v.x, v.y, v.z, v.w};
#pragma unroll
        for (int j = 0; j < 4; ++j) {
            u16 hb = f2bf(vv[j]);
            lh[c4 + j][k] = hb;
            ll[c4 + j][k] = f2bf(vv[j] - bf2f(hb));
        }
    }
    __syncthreads();
#pragma unroll
    for (int u = 0; u < 4; ++u) {
        int n = kr + u * 16;
        ushort4 hv, lv;
        u16* hp = (u16*)&hv; u16* lp = (u16*)&lv;
#pragma unroll
        for (int j = 0; j < 4; ++j) { hp[j] = lh[n][c4 + j]; lp[j] = ll[n][c4 + j]; }
        *(ushort4*)&th[(size_t)(n0 + n) * DM + k0 + c4] = hv;
        *(ushort4*)&tl[(size_t)(n0 + n) * DM + k0 + c4] = lv;
    }
}

// ---------- transpose V f16 [bh][s][d] -> vt [bh][d][s] ----------
__global__ __launch_bounds__(256) void vtrans(const _Float16* __restrict__ v,
                                              _Float16* __restrict__ vt) {
    __shared__ _Float16 ts[64][72];
    int bh = blockIdx.y, s0 = blockIdx.x * 64, t = threadIdx.x;
#pragma unroll
    for (int u = 0; u < 2; ++u) {
        int clin = u * 256 + t;
        int sr = clin >> 3, c = clin & 7;
        f16x8 val = *(const f16x8*)&v[((size_t)bh * SLEN + s0 + sr) * DK + c * 8];
#pragma unroll
        for (int j = 0; j < 8; ++j) ts[c * 8 + j][sr] = val[j];
    }
    __syncthreads();
    int d = t >> 2, sg = t & 3;
#pragma unroll
    for (int u = 0; u < 2; ++u) {
        int s = sg * 16 + u * 8;
        f16x8 w;
#pragma unroll
        for (int j = 0; j < 8; ++j) w[j] = ts[d][s + j];
        *(f16x8*)&vt[((size_t)bh * DK + d) * SLEN + s0 + s] = w;
    }
}

// ---------- split-bf16 3-pass MFMA GEMM: C = A[4096x1024] @ Bt^T + bias ----------
// EPI 0: fp32 row-major out.  EPI 1: f16 head-split qkv out (q scaled 1/8).
template<int BN, int EPI>
__global__ __launch_bounds__(256) void gemm_mfma(
    const u16* __restrict__ Ah, const u16* __restrict__ Al,
    const u16* __restrict__ Bth, const u16* __restrict__ Btl,
    const float* __restrict__ b0, const float* __restrict__ b1, const float* __restrict__ b2,
    float* __restrict__ outf, _Float16* __restrict__ outh)
{
    constexpr int WM = (BN == 128) ? 2 : 4;
    constexpr int WN = 4 / WM;
    constexpr int MF = 8 / WM;      // 16-row frags per wave in M
    constexpr int BISS = BN / 64;
    __shared__ __align__(16) u16 sAh[128 * 32], sAl[128 * 32];
    __shared__ __align__(16) u16 sBh[BN * 32],  sBl[BN * 32];
    const int tid = threadIdx.x, wid = tid >> 6, lane = tid & 63;
    const int lq = lane & 15, lk = lane >> 4;
    const int wm = wid / WN, wn = wid % WN;
    const int bm = blockIdx.x * 128, bn = blockIdx.y * BN;

    const f32x4 fz = {0.f, 0.f, 0.f, 0.f};
    f32x4 acc[MF][4];
#pragma unroll
    for (int i = 0; i < MF; ++i)
#pragma unroll
        for (int j = 0; j < 4; ++j) acc[i][j] = fz;

    for (int k0 = 0; k0 < DM; k0 += 32) {
        __syncthreads();
#pragma unroll
        for (int u = 0; u < 2; ++u) {   // A: 128 rows x 32k, hi+lo
            int clin = u * 256 + tid, row = clin >> 2, c = (clin & 3) ^ ((row >> 1) & 3);
            size_t goff = (size_t)(bm + row) * DM + k0 + c * 8;
            int loff = (u * 256 + wid * 64) * 16;
            gload16(Ah + goff, (char*)sAh + loff);
            gload16(Al + goff, (char*)sAl + loff);
        }
#pragma unroll
        for (int u = 0; u < BISS; ++u) {   // B: BN rows x 32k, hi+lo
            int clin = u * 256 + tid, row = clin >> 2, c = (clin & 3) ^ ((row >> 1) & 3);
            size_t goff = (size_t)(bn + row) * DM + k0 + c * 8;
            int loff = (u * 256 + wid * 64) * 16;
            gload16(Bth + goff, (char*)sBh + loff);
            gload16(Btl + goff, (char*)sBl + loff);
        }
        __syncthreads();

        s16x8 avh[MF], avl[MF], bvh[4], bvl[4];
#pragma unroll
        for (int i = 0; i < MF; ++i) {
            int row = wm * (MF * 16) + i * 16 + lq;
            int off = row * 32 + ((lk ^ ((row >> 1) & 3)) << 3);
            avh[i] = *(const s16x8*)&sAh[off];
            avl[i] = *(const s16x8*)&sAl[off];
        }
#pragma unroll
        for (int j = 0; j < 4; ++j) {
            int row = wn * 64 + j * 16 + lq;
            int off = row * 32 + ((lk ^ ((row >> 1) & 3)) << 3);
            bvh[j] = *(const s16x8*)&sBh[off];
            bvl[j] = *(const s16x8*)&sBl[off];
        }
#pragma unroll
        for (int i = 0; i < MF; ++i)
#pragma unroll
            for (int j = 0; j < 4; ++j) {
                acc[i][j] = MFMA_BF16(avh[i], bvh[j], acc[i][j]);
                acc[i][j] = MFMA_BF16(avh[i], bvl[j], acc[i][j]);
                acc[i][j] = MFMA_BF16(avl[i], bvh[j], acc[i][j]);
            }
    }

    // epilogue
#pragma unroll
    for (int j = 0; j < 4; ++j) {
        int n = bn + wn * 64 + j * 16 + lq;
#pragma unroll
        for (int i = 0; i < MF; ++i) {
#pragma unroll
            for (int r = 0; r < 4; ++r) {
                int m = bm + wm * (MF * 16) + i * 16 + lk * 4 + r;
                float v = acc[i][j][r];
                if constexpr (EPI == 0) {
                    outf[(size_t)m * DM + n] = v + b0[n];
                } else {
                    int mat = n >> 10, nl = n & 1023;
                    const float* bp = (mat == 0) ? b0 : ((mat == 1) ? b1 : b2);
                    float val = v + bp[nl];
                    if (mat == 0) val *= 0.125f;
                    int h_ = nl >> 6, d = nl & 63;
                    int b_ = m >> 11, s = m & (SLEN - 1);
                    outh[(((size_t)mat * 2 + b_) * NH + h_) * (SLEN * DK)
                         + (size_t)s * DK + d] = (_Float16)val;
                }
            }
        }
    }
}

// ---------- f16 MFMA flash attention ----------
// q,k: f16 [bh][s][d]; vt: f16 [bh][d][s]; out: bf16 hi/lo [4096][1024]
__global__ __launch_bounds__(512) void attn_mfma(
    const _Float16* __restrict__ qf, const _Float16* __restrict__ kf,
    const _Float16* __restrict__ vt, u16* __restrict__ aoh, u16* __restrict__ aol)
{
    __shared__ __align__(16) _Float16 Ks[64 * 64], Vs[64 * 64];
    __shared__ __align__(16) _Float16 Ps[8 * 16 * 64];
    const int tid = threadIdx.x, wid = tid >> 6, lane = tid & 63;
    const int lq = lane & 15, lk = lane >> 4;
    const int bh = blockIdx.y, q0 = blockIdx.x * 128;
    _Float16* Pw = &Ps[wid * 16 * 64];

    // Q fragments in registers (wave owns 16 rows), already scaled by 1/8
    f16x8 qfr[2];
#pragma unroll
    for (int kk = 0; kk < 2; ++kk)
        qfr[kk] = *(const f16x8*)&qf[((size_t)bh * SLEN + q0 + wid * 16 + lq) * DK + kk * 32 + lk * 8];

    const f32x4 fz = {0.f, 0.f, 0.f, 0.f};
    f32x4 o_[4];
    float m_[4], l_[4];
#pragma unroll
    for (int r = 0; r < 4; ++r) { m_[r] = -1e30f; l_[r] = 0.f; }
#pragma unroll
    for (int d = 0; d < 4; ++d) o_[d] = fz;

    for (int t = 0; t < SLEN / 64; ++t) {
        __syncthreads();
        {   // stage K tile [64 kv][64 d] and V^T tile [64 d][64 s], swizzled chunks
            int row = tid >> 3, c = (tid & 7) ^ (row & 7);
            gload16(kf + ((size_t)bh * SLEN + t * 64 + row) * DK + c * 8,
                    (char*)Ks + wid * 1024 + 0);
            gload16(vt + ((size_t)bh * DK + row) * SLEN + t * 64 + c * 8,
                    (char*)Vs + wid * 1024 + 0);
        }
        __syncthreads();

        // S = Q K^T (pre-scaled)
        f32x4 sa[4];
#pragma unroll
        for (int nf = 0; nf < 4; ++nf) sa[nf] = fz;
#pragma unroll
        for (int kk = 0; kk < 2; ++kk)
#pragma unroll
            for (int nf = 0; nf < 4; ++nf) {
                int krow = nf * 16 + lq;
                f16x8 kb = *(const f16x8*)&Ks[krow * 64 + (((kk * 4 + lk) ^ (krow & 7)) << 3)];
                sa[nf] = MFMA_F16(qfr[kk], kb, sa[nf]);
            }

        // online softmax (rows = lk*4 + r, replicated over lq group)
#pragma unroll
        for (int r = 0; r < 4; ++r) {
            float mx = fmaxf(fmaxf(sa[0][r], sa[1][r]), fmaxf(sa[2][r], sa[3][r]));
            mx = fmaxf(mx, __shfl_xor(mx, 1));
            mx = fmaxf(mx, __shfl_xor(mx, 2));
            mx = fmaxf(mx, __shfl_xor(mx, 4));
            mx = fmaxf(mx, __shfl_xor(mx, 8));
            float mn = fmaxf(m_[r], mx);
            float al = __expf(m_[r] - mn);
            m_[r] = mn;
            float rs = 0.f;
#pragma unroll
            for (int nf = 0; nf < 4; ++nf) { sa[nf][r] = __expf(sa[nf][r] - mn); rs += sa[nf][r]; }
            rs += __shfl_xor(rs, 1);
            rs += __shfl_xor(rs, 2);
            rs += __shfl_xor(rs, 4);
            rs += __shfl_xor(rs, 8);
            l_[r] = l_[r] * al + rs;
#pragma unroll
            for (int d = 0; d < 4; ++d) o_[d][r] *= al;
        }

        // publish P (f16) to per-wave LDS, swizzled
#pragma unroll
        for (int nf = 0; nf < 4; ++nf)
#pragma unroll
            for (int r = 0; r < 4; ++r) {
                int rr = lk * 4 + r;
                int cv = nf * 16 + lq;
                Pw[rr * 64 + (((cv >> 3) ^ (rr & 7)) << 3) + (cv & 7)] = (_Float16)sa[nf][r];
            }

        // O += P V
#pragma unroll
        for (int kk = 0; kk < 2; ++kk) {
            f16x8 pa = *(const f16x8*)&Pw[lq * 64 + (((kk * 4 + lk) ^ (lq & 7)) << 3)];
#pragma unroll
            for (int d = 0; d < 4; ++d) {
                int vrow = d * 16 + lq;
                f16x8 vb = *(const f16x8*)&Vs[vrow * 64 + (((kk * 4 + lk) ^ (vrow & 7)) << 3)];
                o_[d] = MFMA_F16(pa, vb, o_[d]);
            }
        }
    }

    // epilogue: normalize, split to bf16 hi/lo, write [4096][1024]
    const int b_ = bh >> 4, h_ = bh & 15;
#pragma unroll
    for (int r = 0; r < 4; ++r) {
        float inv = 1.0f / l_[r];
        int srow = q0 + wid * 16 + lk * 4 + r;
        size_t rb = ((size_t)(b_ * SLEN + srow)) * DM + h_ * 64;
#pragma unroll
        for (int d = 0; d < 4; ++d) {
            float v = o_[d][r] * inv;
            u16 hb = f2bf(v);
            u16 lb = f2bf(v - bf2f(hb));
            aoh[rb + d * 16 + lq] = hb;
            aol[rb + d * 16 + lq] = lb;
        }
    }
}

extern "C" void kernel_launch(void* const* d_in, const int* in_sizes, int n_in,
                              void* d_out, int out_size, void* d_ws, size_t ws_size,
                              hipStream_t stream) {
    const float* x  = (const float*)d_in[0];
    const float* Wq = (const float*)d_in[1];
    const float* bq = (const float*)d_in[2];
    const float* Wk = (const float*)d_in[3];
    const float* bk = (const float*)d_in[4];
    const float* Wv = (const float*)d_in[5];
    const float* bv = (const float*)d_in[6];
    const float* Wo = (const float*)d_in[7];
    const float* bo = (const float*)d_in[8];
    float* out = (float*)d_out;

    if (ws_size < (size_t)64 * 1024 * 1024) return;
    char* W = (char*)d_ws;
    u16* xh   = (u16*)(W);                          // 8MB, dead after QKV GEMM
    u16* xl   = (u16*)(W + ((size_t)8  << 20));     // 8MB, dead after QKV GEMM
    u16* wqh  = (u16*)(W + ((size_t)16 << 20));     // 6MB  (Wqkv^T hi, 3072x1024)
    u16* wql  = (u16*)(W + ((size_t)22 << 20));     // 6MB
    u16* woh  = (u16*)(W + ((size_t)28 << 20));     // 2MB
    u16* wol  = (u16*)(W + ((size_t)30 << 20));     // 2MB
    _Float16* qkvf = (_Float16*)(W + ((size_t)32 << 20)); // 24MB f16 q|k|v head-split
    u16* aol  = (u16*)(W + ((size_t)56 << 20));     // 8MB
    _Float16* vtf = (_Float16*)(W);                 // 8MB, reuses xh region
    u16* aoh  = (u16*)(W + ((size_t)8 << 20));      // 8MB, reuses xl region

    cvt_x<<<dim3(MROWS * DM / 1024), dim3(256), 0, stream>>>(x, xh, xl);
    cvt_wt<<<dim3(16, 16), dim3(256), 0, stream>>>(Wq, wqh, wql);
    cvt_wt<<<dim3(16, 16), dim3(256), 0, stream>>>(Wk, wqh + 1024 * 1024, wql + 1024 * 1024);
    cvt_wt<<<dim3(16, 16), dim3(256), 0, stream>>>(Wv, wqh + 2 * 1024 * 1024, wql + 2 * 1024 * 1024);
    cvt_wt<<<dim3(16, 16), dim3(256), 0, stream>>>(Wo, woh, wol);

    gemm_mfma<128, 1><<<dim3(32, 24), dim3(256), 0, stream>>>(
        xh, xl, wqh, wql, bq, bk, bv, nullptr, qkvf);

    vtrans<<<dim3(32, 32), dim3(256), 0, stream>>>(qkvf + (size_t)2 * 4194304, vtf);

    attn_mfma<<<dim3(16, 32), dim3(512), 0, stream>>>(
        qkvf, qkvf + (size_t)4194304, vtf, aoh, aol);

    gemm_mfma<64, 0><<<dim3(32, 16), dim3(256), 0, stream>>>(
        aoh, aol, woh, wol, bo, bo, bo, out, nullptr);
}

// Round 3
// 223.532 us; speedup vs baseline: 5.3370x; 1.1331x over previous
//
#include <hip/hip_runtime.h>
#include <math.h>

#define DM    1024
#define NH    16
#define DK    64
#define SLEN  2048
#define NB    2
#define MROWS (NB*SLEN)   // 4096
#define QSCALE 0.1803368801111204f   // (1/8) * log2(e)

typedef unsigned short u16;
typedef short  s16x8 __attribute__((ext_vector_type(8)));
typedef _Float16 f16x8 __attribute__((ext_vector_type(8)));
typedef float  f32x4 __attribute__((ext_vector_type(4)));

#define MFMA_BF16(a,b,c) __builtin_amdgcn_mfma_f32_16x16x32_bf16(a,b,c,0,0,0)
#define MFMA_F16(a,b,c)  __builtin_amdgcn_mfma_f32_16x16x32_f16(a,b,c,0,0,0)

__device__ __forceinline__ void gload16(const void* g, void* l) {
    __builtin_amdgcn_global_load_lds((const __attribute__((address_space(1))) void*)g,
                                     (__attribute__((address_space(3))) void*)l, 16, 0, 0);
}
__device__ __forceinline__ f16x8 as_h(s16x8 v) {
    union { s16x8 s; f16x8 h; } u; u.s = v; return u.h;
}
__device__ __forceinline__ float exp2_hw(float x) {
    float r; asm("v_exp_f32 %0, %1" : "=v"(r) : "v"(x)); return r;
}
__device__ __forceinline__ u16 f2bf(float x) {
    union { float f; unsigned int u; } v; v.f = x;
    unsigned int r = v.u + 0x7fffu + ((v.u >> 16) & 1u);
    return (u16)(r >> 16);
}
__device__ __forceinline__ float bf2f(u16 u) {
    union { unsigned int u; float f; } v; v.u = ((unsigned int)u) << 16;
    return v.f;
}
#define VMCNT0() asm volatile("s_waitcnt vmcnt(0)" ::: "memory")
#define BAR()    __builtin_amdgcn_s_barrier()

// ---------- x (f32) -> hi/lo f16 split ----------
__global__ __launch_bounds__(256) void cvt_x(const float* __restrict__ in,
                                             _Float16* __restrict__ h, _Float16* __restrict__ l) {
    int i = (blockIdx.x * 256 + threadIdx.x) * 4;
    float4 v = *(const float4*)&in[i];
    float vv[4] = {v.x, v.y, v.z, v.w};
    _Float16 hv[4], lv[4];
#pragma unroll
    for (int j = 0; j < 4; ++j) {
        hv[j] = (_Float16)vv[j];
        lv[j] = (_Float16)(vv[j] - (float)hv[j]);
    }
    *(ushort4*)&h[i] = *(ushort4*)hv;
    *(ushort4*)&l[i] = *(ushort4*)lv;
}

// ---------- W (f32 [k][n]) -> W^T f16 [n][k] ----------
__global__ __launch_bounds__(256) void cvt_w_f16(const float* __restrict__ W,
                                                 _Float16* __restrict__ wt) {
    __shared__ _Float16 ts[64][72];
    int k0 = blockIdx.x * 64, n0 = blockIdx.y * 64;
    int t = threadIdx.x, kr = t >> 4, c4 = (t & 15) * 4;
#pragma unroll
    for (int u = 0; u < 4; ++u) {
        int k = kr + u * 16;
        float4 v = *(const float4*)&W[(size_t)(k0 + k) * DM + n0 + c4];
        float vv[4] = {v.x, v.y, v.z, v.w};
#pragma unroll
        for (int j = 0; j < 4; ++j) ts[c4 + j][k] = (_Float16)vv[j];
    }
    __syncthreads();
#pragma unroll
    for (int u = 0; u < 4; ++u) {
        int n = kr + u * 16;
        _Float16 hv[4];
#pragma unroll
        for (int j = 0; j < 4; ++j) hv[j] = ts[n][c4 + j];
        *(ushort4*)&wt[(size_t)(n0 + n) * DM + k0 + c4] = *(ushort4*)hv;
    }
}

// ---------- Wo (f32 [k][n]) -> W^T hi/lo bf16 [n][k] ----------
__global__ __launch_bounds__(256) void cvt_w_bf(const float* __restrict__ W,
                                                u16* __restrict__ th, u16* __restrict__ tl) {
    __shared__ u16 lh[64][72], ll[64][72];
    int k0 = blockIdx.x * 64, n0 = blockIdx.y * 64;
    int t = threadIdx.x, kr = t >> 4, c4 = (t & 15) * 4;
#pragma unroll
    for (int u = 0; u < 4; ++u) {
        int k = kr + u * 16;
        float4 v = *(const float4*)&W[(size_t)(k0 + k) * DM + n0 + c4];
        float vv[4] = {v.x, v.y, v.z, v.w};
#pragma unroll
        for (int j = 0; j < 4; ++j) {
            u16 hb = f2bf(vv[j]);
            lh[c4 + j][k] = hb;
            ll[c4 + j][k] = f2bf(vv[j] - bf2f(hb));
        }
    }
    __syncthreads();
#pragma unroll
    for (int u = 0; u < 4; ++u) {
        int n = kr + u * 16;
        ushort4 hv, lv;
        u16* hp = (u16*)&hv; u16* lp = (u16*)&lv;
#pragma unroll
        for (int j = 0; j < 4; ++j) { hp[j] = lh[n][c4 + j]; lp[j] = ll[n][c4 + j]; }
        *(ushort4*)&th[(size_t)(n0 + n) * DM + k0 + c4] = hv;
        *(ushort4*)&tl[(size_t)(n0 + n) * DM + k0 + c4] = lv;
    }
}

// ---------- transpose V f16 [bh][s][d] -> vt [bh][d][s] ----------
__global__ __launch_bounds__(256) void vtrans(const _Float16* __restrict__ v,
                                              _Float16* __restrict__ vt) {
    __shared__ _Float16 ts[64][72];
    int bh = blockIdx.y, s0 = blockIdx.x * 64, t = threadIdx.x;
#pragma unroll
    for (int u = 0; u < 2; ++u) {
        int clin = u * 256 + t, sr = clin >> 3, c = clin & 7;
        f16x8 val = *(const f16x8*)&v[((size_t)bh * SLEN + s0 + sr) * DK + c * 8];
#pragma unroll
        for (int j = 0; j < 8; ++j) ts[c * 8 + j][sr] = val[j];
    }
    __syncthreads();
    int d = t >> 2, sg = t & 3;
#pragma unroll
    for (int u = 0; u < 2; ++u) {
        int s = sg * 16 + u * 8;
        f16x8 w;
#pragma unroll
        for (int j = 0; j < 8; ++j) w[j] = ts[d][s + j];
        *(f16x8*)&vt[((size_t)bh * DK + d) * SLEN + s0 + s] = w;
    }
}

// ---------- MFMA GEMM, 2-phase prefetch.  MODE 0: f16 2-pass, qkv epilogue.
//                                          MODE 1: bf16 3-pass, f32 epilogue. ----------
template<int MODE>
__global__ __launch_bounds__(256) void gemm_k(
    const u16* __restrict__ Ah, const u16* __restrict__ Al,
    const u16* __restrict__ Bh, const u16* __restrict__ Bl,
    const float* __restrict__ b0, const float* __restrict__ b1, const float* __restrict__ b2,
    float* __restrict__ outf, _Float16* __restrict__ outh)
{
    __shared__ __align__(16) u16 sAh[2][4096], sAl[2][4096], sBh[2][4096];
    __shared__ __align__(16) u16 sBl[2][MODE == 1 ? 4096 : 4];
    const int tid = threadIdx.x, wid = tid >> 6, lane = tid & 63;
    const int lq = lane & 15, lk = lane >> 4;
    const int wm = wid >> 1, wn = wid & 1;
    const int bm = blockIdx.x * 128, bn = blockIdx.y * 128;

    const f32x4 fz = {0.f, 0.f, 0.f, 0.f};
    f32x4 acc[4][4];
#pragma unroll
    for (int i = 0; i < 4; ++i)
#pragma unroll
        for (int j = 0; j < 4; ++j) acc[i][j] = fz;

    auto stage = [&](int b, int k0) {
#pragma unroll
        for (int u = 0; u < 2; ++u) {
            int idx = u * 256 + tid, row = idx >> 2, c = (idx & 3) ^ ((row >> 1) & 3);
            size_t ga = (size_t)(bm + row) * DM + k0 + c * 8;
            size_t gb = (size_t)(bn + row) * DM + k0 + c * 8;
            int lo = (u * 256 + wid * 64) * 16;
            gload16(Ah + ga, (char*)&sAh[b][0] + lo);
            gload16(Al + ga, (char*)&sAl[b][0] + lo);
            gload16(Bh + gb, (char*)&sBh[b][0] + lo);
            if constexpr (MODE == 1) gload16(Bl + gb, (char*)&sBl[b][0] + lo);
        }
    };
    auto compute = [&](int b) {
        s16x8 avh[4], avl[4], bvh[4], bvl[4];
#pragma unroll
        for (int i = 0; i < 4; ++i) {
            int row = wm * 64 + i * 16 + lq;
            int off = row * 32 + ((lk ^ ((row >> 1) & 3)) << 3);
            avh[i] = *(const s16x8*)&sAh[b][off];
            avl[i] = *(const s16x8*)&sAl[b][off];
        }
#pragma unroll
        for (int j = 0; j < 4; ++j) {
            int row = wn * 64 + j * 16 + lq;
            int off = row * 32 + ((lk ^ ((row >> 1) & 3)) << 3);
            bvh[j] = *(const s16x8*)&sBh[b][off];
            if constexpr (MODE == 1) bvl[j] = *(const s16x8*)&sBl[b][off];
        }
#pragma unroll
        for (int i = 0; i < 4; ++i)
#pragma unroll
            for (int j = 0; j < 4; ++j) {
                if constexpr (MODE == 0) {
                    acc[i][j] = MFMA_F16(as_h(avh[i]), as_h(bvh[j]), acc[i][j]);
                    acc[i][j] = MFMA_F16(as_h(avl[i]), as_h(bvh[j]), acc[i][j]);
                } else {
                    acc[i][j] = MFMA_BF16(avh[i], bvh[j], acc[i][j]);
                    acc[i][j] = MFMA_BF16(avh[i], bvl[j], acc[i][j]);
                    acc[i][j] = MFMA_BF16(avl[i], bvh[j], acc[i][j]);
                }
            }
    };

    int buf = 0;
    stage(0, 0);
    VMCNT0(); BAR();
    for (int t = 0; t < 31; ++t) {
        stage(buf ^ 1, (t + 1) * 32);
        compute(buf);
        VMCNT0(); BAR();
        buf ^= 1;
    }
    compute(buf);

    // epilogue
#pragma unroll
    for (int j = 0; j < 4; ++j) {
        int n = bn + wn * 64 + j * 16 + lq;
#pragma unroll
        for (int i = 0; i < 4; ++i) {
#pragma unroll
            for (int r = 0; r < 4; ++r) {
                int m = bm + wm * 64 + i * 16 + lk * 4 + r;
                float v = acc[i][j][r];
                if constexpr (MODE == 1) {
                    outf[(size_t)m * DM + n] = v + b0[n];
                } else {
                    int mat = n >> 10, nl = n & 1023;
                    const float* bp = (mat == 0) ? b0 : ((mat == 1) ? b1 : b2);
                    float val = v + bp[nl];
                    if (mat == 0) val *= QSCALE;
                    int h_ = nl >> 6, d = nl & 63;
                    int b_ = m >> 11, s = m & (SLEN - 1);
                    outh[(((size_t)mat * 2 + b_) * NH + h_) * (SLEN * DK)
                         + (size_t)s * DK + d] = (_Float16)val;
                }
            }
        }
    }
}

// ---------- f16 MFMA flash attention, 2-phase prefetch, exp2 softmax ----------
// q,k: f16 [bh][s][d] (q pre-scaled by log2e/8); vt: f16 [bh][d][s]
// out: bf16 hi/lo [4096][1024]
__global__ __launch_bounds__(256) void attn_mfma(
    const _Float16* __restrict__ qf, const _Float16* __restrict__ kf,
    const _Float16* __restrict__ vt, u16* __restrict__ aoh, u16* __restrict__ aol)
{
    __shared__ __align__(16) _Float16 Ks[2][64 * 64], Vs[2][64 * 64];
    __shared__ __align__(16) _Float16 Ps[4][16 * 64];
    const int tid = threadIdx.x, wid = tid >> 6, lane = tid & 63;
    const int lq = lane & 15, lk = lane >> 4;
    // bijective XCD swizzle: 4 consecutive bh per XCD -> KV panels L2-resident
    const int phys = blockIdx.x;
    const int virt = (phys & 7) * 128 + (phys >> 3);
    const int bh = virt >> 5, q0 = (virt & 31) << 6;
    _Float16* Pw = &Ps[wid][0];

    f16x8 qfr[2];
#pragma unroll
    for (int kk = 0; kk < 2; ++kk)
        qfr[kk] = *(const f16x8*)&qf[((size_t)bh * SLEN + q0 + wid * 16 + lq) * DK + kk * 32 + lk * 8];

    const f32x4 fz = {0.f, 0.f, 0.f, 0.f};
    f32x4 o_[4];
    float m_[4], lp[4];
#pragma unroll
    for (int r = 0; r < 4; ++r) { m_[r] = -1e30f; lp[r] = 0.f; }
#pragma unroll
    for (int d = 0; d < 4; ++d) o_[d] = fz;

    auto stage = [&](int b, int t) {
#pragma unroll
        for (int u = 0; u < 2; ++u) {
            int idx = u * 256 + tid, row = idx >> 3, c = (idx & 7) ^ (row & 7);
            int lo = (u * 256 + wid * 64) * 16;
            gload16(kf + ((size_t)bh * SLEN + t * 64 + row) * DK + c * 8,
                    (char*)&Ks[b][0] + lo);
            gload16(vt + ((size_t)bh * DK + row) * SLEN + t * 64 + c * 8,
                    (char*)&Vs[b][0] + lo);
        }
    };
    auto compute = [&](int b) {
        // S = Q K^T  (log2-domain scores)
        f32x4 sa[4];
#pragma unroll
        for (int nf = 0; nf < 4; ++nf) sa[nf] = fz;
#pragma unroll
        for (int kk = 0; kk < 2; ++kk)
#pragma unroll
            for (int nf = 0; nf < 4; ++nf) {
                int krow = nf * 16 + lq;
                f16x8 kb = *(const f16x8*)&Ks[b][krow * 64 + (((kk * 4 + lk) ^ (krow & 7)) << 3)];
                sa[nf] = MFMA_F16(qfr[kk], kb, sa[nf]);
            }
        // online softmax, defer-rescale (THR = 8 in log2 units)
#pragma unroll
        for (int r = 0; r < 4; ++r) {
            float mx = fmaxf(fmaxf(sa[0][r], sa[1][r]), fmaxf(sa[2][r], sa[3][r]));
            mx = fmaxf(mx, __shfl_xor(mx, 1));
            mx = fmaxf(mx, __shfl_xor(mx, 2));
            mx = fmaxf(mx, __shfl_xor(mx, 4));
            mx = fmaxf(mx, __shfl_xor(mx, 8));
            bool need = mx > m_[r] + 8.0f;
            if (__any(need)) {
                float al = need ? exp2_hw(m_[r] - mx) : 1.0f;
                if (need) m_[r] = mx;
                lp[r] *= al;
#pragma unroll
                for (int d = 0; d < 4; ++d) o_[d][r] *= al;
            }
#pragma unroll
            for (int nf = 0; nf < 4; ++nf) {
                float p = exp2_hw(sa[nf][r] - m_[r]);
                sa[nf][r] = p;
                lp[r] += p;
            }
        }
        // publish P (f16, per-wave LDS, swizzled)
#pragma unroll
        for (int nf = 0; nf < 4; ++nf)
#pragma unroll
            for (int r = 0; r < 4; ++r) {
                int rr = lk * 4 + r, cv = nf * 16 + lq;
                Pw[rr * 64 + (((cv >> 3) ^ (rr & 7)) << 3) + (cv & 7)] = (_Float16)sa[nf][r];
            }
        // O += P V
#pragma unroll
        for (int kk = 0; kk < 2; ++kk) {
            f16x8 pa = *(const f16x8*)&Pw[lq * 64 + (((kk * 4 + lk) ^ (lq & 7)) << 3)];
#pragma unroll
            for (int d = 0; d < 4; ++d) {
                int vrow = d * 16 + lq;
                f16x8 vb = *(const f16x8*)&Vs[b][vrow * 64 + (((kk * 4 + lk) ^ (vrow & 7)) << 3)];
                o_[d] = MFMA_F16(pa, vb, o_[d]);
            }
        }
    };

    int buf = 0;
    stage(0, 0);
    VMCNT0(); BAR();
    for (int t = 0; t < SLEN / 64 - 1; ++t) {
        stage(buf ^ 1, t + 1);
        compute(buf);
        VMCNT0(); BAR();
        buf ^= 1;
    }
    compute(buf);

    // epilogue: reduce l, normalize, bf16 hi/lo split
    const int b_ = bh >> 4, h_ = bh & 15;
#pragma unroll
    for (int r = 0; r < 4; ++r) {
        float l = lp[r];
        l += __shfl_xor(l, 1);
        l += __shfl_xor(l, 2);
        l += __shfl_xor(l, 4);
        l += __shfl_xor(l, 8);
        float inv = 1.0f / l;
        int srow = q0 + wid * 16 + lk * 4 + r;
        size_t rb = ((size_t)(b_ * SLEN + srow)) * DM + h_ * 64;
#pragma unroll
        for (int d = 0; d < 4; ++d) {
            float v = o_[d][r] * inv;
            u16 hb = f2bf(v);
            aoh[rb + d * 16 + lq] = hb;
            aol[rb + d * 16 + lq] = f2bf(v - bf2f(hb));
        }
    }
}

extern "C" void kernel_launch(void* const* d_in, const int* in_sizes, int n_in,
                              void* d_out, int out_size, void* d_ws, size_t ws_size,
                              hipStream_t stream) {
    const float* x  = (const float*)d_in[0];
    const float* Wq = (const float*)d_in[1];
    const float* bq = (const float*)d_in[2];
    const float* Wk = (const float*)d_in[3];
    const float* bk = (const float*)d_in[4];
    const float* Wv = (const float*)d_in[5];
    const float* bv = (const float*)d_in[6];
    const float* Wo = (const float*)d_in[7];
    const float* bo = (const float*)d_in[8];
    float* out = (float*)d_out;

    if (ws_size < (size_t)58 * 1024 * 1024) return;
    char* W = (char*)d_ws;
    _Float16* xh   = (_Float16*)(W);                       // 8MB, dead after QKV
    _Float16* xl   = (_Float16*)(W + ((size_t)8  << 20));  // 8MB, dead after QKV
    _Float16* wqkv = (_Float16*)(W + ((size_t)16 << 20));  // 6MB  Wqkv^T f16
    u16* woh       = (u16*)(W + ((size_t)22 << 20));       // 2MB
    u16* wol       = (u16*)(W + ((size_t)24 << 20));       // 2MB
    _Float16* qkvf = (_Float16*)(W + ((size_t)26 << 20));  // 24MB q|k|v head-split
    u16* aol       = (u16*)(W + ((size_t)50 << 20));       // 8MB
    _Float16* vtf  = (_Float16*)(W);                       // reuse xh
    u16* aoh       = (u16*)(W + ((size_t)8 << 20));        // reuse xl

    cvt_x<<<dim3(MROWS * DM / 1024), dim3(256), 0, stream>>>(x, xh, xl);
    cvt_w_f16<<<dim3(16, 16), dim3(256), 0, stream>>>(Wq, wqkv);
    cvt_w_f16<<<dim3(16, 16), dim3(256), 0, stream>>>(Wk, wqkv + 1024 * 1024);
    cvt_w_f16<<<dim3(16, 16), dim3(256), 0, stream>>>(Wv, wqkv + 2 * 1024 * 1024);
    cvt_w_bf<<<dim3(16, 16), dim3(256), 0, stream>>>(Wo, woh, wol);

    gemm_k<0><<<dim3(32, 24), dim3(256), 0, stream>>>(
        (const u16*)xh, (const u16*)xl, (const u16*)wqkv, nullptr,
        bq, bk, bv, nullptr, qkvf);

    vtrans<<<dim3(32, 32), dim3(256), 0, stream>>>(qkvf + (size_t)2 * 4194304, vtf);

    attn_mfma<<<dim3(1024), dim3(256), 0, stream>>>(
        qkvf, qkvf + (size_t)4194304, vtf, aoh, aol);

    gemm_k<1><<<dim3(32, 8), dim3(256), 0, stream>>>(
        aoh, aol, woh, wol, bo, bo, bo, out, nullptr);
}

// Round 4
// 175.070 us; speedup vs baseline: 6.8143x; 1.2768x over previous
//
#include <hip/hip_runtime.h>
#include <math.h>

#define DM    1024
#define NH    16
#define DK    64
#define SLEN  2048
#define NB    2
#define MROWS (NB*SLEN)   // 4096
#define QSCALE 0.1803368801111204f   // (1/8) * log2(e)

typedef unsigned short u16;
typedef unsigned int   u32;
typedef short  s16x8 __attribute__((ext_vector_type(8)));
typedef _Float16 f16x8 __attribute__((ext_vector_type(8)));
typedef float  f32x4  __attribute__((ext_vector_type(4)));
typedef float  f32x16 __attribute__((ext_vector_type(16)));

#define MFMA_F16(a,b,c)   __builtin_amdgcn_mfma_f32_16x16x32_f16(a,b,c,0,0,0)
#define MFMA32_F16(a,b,c) __builtin_amdgcn_mfma_f32_32x32x16_f16(a,b,c,0,0,0)

__device__ __forceinline__ void gload16(const void* g, void* l) {
    __builtin_amdgcn_global_load_lds((const __attribute__((address_space(1))) void*)g,
                                     (__attribute__((address_space(3))) void*)l, 16, 0, 0);
}
__device__ __forceinline__ f16x8 as_h(s16x8 v) {
    union { s16x8 s; f16x8 h; } u; u.s = v; return u.h;
}
__device__ __forceinline__ float exp2_hw(float x) {
    float r; asm("v_exp_f32 %0, %1" : "=v"(r) : "v"(x)); return r;
}
__device__ __forceinline__ u32 pk2(float a, float b) {   // RNE pack to half2
    union { _Float16 h[2]; u32 u; } x;
    x.h[0] = (_Float16)a; x.h[1] = (_Float16)b;
    return x.u;
}
__device__ __forceinline__ void pl32swap(u32& a, u32& b) {
    asm volatile("v_permlane32_swap_b32 %0, %1" : "+v"(a), "+v"(b));
}
#define VMCNT0() asm volatile("s_waitcnt vmcnt(0)" ::: "memory")
#define BAR()    __builtin_amdgcn_s_barrier()

// ---------- x (f32) -> hi/lo f16 split ----------
__global__ __launch_bounds__(256) void cvt_x(const float* __restrict__ in,
                                             _Float16* __restrict__ h, _Float16* __restrict__ l) {
    int i = (blockIdx.x * 256 + threadIdx.x) * 4;
    float4 v = *(const float4*)&in[i];
    float vv[4] = {v.x, v.y, v.z, v.w};
    _Float16 hv[4], lv[4];
#pragma unroll
    for (int j = 0; j < 4; ++j) {
        hv[j] = (_Float16)vv[j];
        lv[j] = (_Float16)(vv[j] - (float)hv[j]);
    }
    *(ushort4*)&h[i] = *(ushort4*)hv;
    *(ushort4*)&l[i] = *(ushort4*)lv;
}

// ---------- all four W (f32 [k][n]) -> W^T f16 [n][k], one launch ----------
__global__ __launch_bounds__(256) void cvt_w4(
    const float* __restrict__ Wq, const float* __restrict__ Wk,
    const float* __restrict__ Wv, const float* __restrict__ Wo,
    _Float16* __restrict__ wqkv, _Float16* __restrict__ wo) {
    __shared__ _Float16 ts[64][72];
    const int z = blockIdx.z;
    const float* W = (z == 0) ? Wq : (z == 1) ? Wk : (z == 2) ? Wv : Wo;
    _Float16* dst = (z < 3) ? (wqkv + (size_t)z * DM * DM) : wo;
    int k0 = blockIdx.x * 64, n0 = blockIdx.y * 64;
    int t = threadIdx.x, kr = t >> 4, c4 = (t & 15) * 4;
#pragma unroll
    for (int u = 0; u < 4; ++u) {
        int k = kr + u * 16;
        float4 v = *(const float4*)&W[(size_t)(k0 + k) * DM + n0 + c4];
        float vv[4] = {v.x, v.y, v.z, v.w};
#pragma unroll
        for (int j = 0; j < 4; ++j) ts[c4 + j][k] = (_Float16)vv[j];
    }
    __syncthreads();
#pragma unroll
    for (int u = 0; u < 4; ++u) {
        int n = kr + u * 16;
        _Float16 hv[4];
#pragma unroll
        for (int j = 0; j < 4; ++j) hv[j] = ts[n][c4 + j];
        *(ushort4*)&dst[(size_t)(n0 + n) * DM + k0 + c4] = *(ushort4*)hv;
    }
}

// ---------- f16 2-pass MFMA GEMM, 2-phase prefetch ----------
// EPI 0: f32 out + bias.  EPI 1: qkv epilogue (q scaled, v written transposed).
template<int EPI>
__global__ __launch_bounds__(256) void gemm_f16(
    const u16* __restrict__ Ah, const u16* __restrict__ Al,
    const u16* __restrict__ Bt,
    const float* __restrict__ b0, const float* __restrict__ b1, const float* __restrict__ b2,
    float* __restrict__ outf, _Float16* __restrict__ qf,
    _Float16* __restrict__ kfp, _Float16* __restrict__ vtp)
{
    __shared__ __align__(16) u16 sAh[2][4096], sAl[2][4096], sB[2][4096];
    const int tid = threadIdx.x, wid = tid >> 6, lane = tid & 63;
    const int lq = lane & 15, lk = lane >> 4;
    const int wm = wid >> 1, wn = wid & 1;
    const int bm = blockIdx.x * 128, bn = blockIdx.y * 128;

    const f32x4 fz = {0.f, 0.f, 0.f, 0.f};
    f32x4 acc[4][4];
#pragma unroll
    for (int i = 0; i < 4; ++i)
#pragma unroll
        for (int j = 0; j < 4; ++j) acc[i][j] = fz;

    auto stage = [&](int b, int k0) {
#pragma unroll
        for (int u = 0; u < 2; ++u) {
            int idx = u * 256 + tid, row = idx >> 2, c = (idx & 3) ^ ((row >> 1) & 3);
            size_t ga = (size_t)(bm + row) * DM + k0 + c * 8;
            size_t gb = (size_t)(bn + row) * DM + k0 + c * 8;
            int lo = (u * 256 + wid * 64) * 16;
            gload16(Ah + ga, (char*)&sAh[b][0] + lo);
            gload16(Al + ga, (char*)&sAl[b][0] + lo);
            gload16(Bt + gb, (char*)&sB[b][0] + lo);
        }
    };
    auto compute = [&](int b) {
        s16x8 avh[4], avl[4], bv[4];
#pragma unroll
        for (int i = 0; i < 4; ++i) {
            int row = wm * 64 + i * 16 + lq;
            int off = row * 32 + ((lk ^ ((row >> 1) & 3)) << 3);
            avh[i] = *(const s16x8*)&sAh[b][off];
            avl[i] = *(const s16x8*)&sAl[b][off];
        }
#pragma unroll
        for (int j = 0; j < 4; ++j) {
            int row = wn * 64 + j * 16 + lq;
            int off = row * 32 + ((lk ^ ((row >> 1) & 3)) << 3);
            bv[j] = *(const s16x8*)&sB[b][off];
        }
        __builtin_amdgcn_s_setprio(1);
#pragma unroll
        for (int i = 0; i < 4; ++i)
#pragma unroll
            for (int j = 0; j < 4; ++j) {
                acc[i][j] = MFMA_F16(as_h(avh[i]), as_h(bv[j]), acc[i][j]);
                acc[i][j] = MFMA_F16(as_h(avl[i]), as_h(bv[j]), acc[i][j]);
            }
        __builtin_amdgcn_s_setprio(0);
    };

    int buf = 0;
    stage(0, 0);
    VMCNT0(); BAR();
    for (int t = 0; t < 31; ++t) {
        stage(buf ^ 1, (t + 1) * 32);
        compute(buf);
        VMCNT0(); BAR();
        buf ^= 1;
    }
    compute(buf);

    // epilogue
#pragma unroll
    for (int j = 0; j < 4; ++j) {
        int n = bn + wn * 64 + j * 16 + lq;
        if constexpr (EPI == 0) {
            float bias = b0[n];
#pragma unroll
            for (int i = 0; i < 4; ++i)
#pragma unroll
                for (int r = 0; r < 4; ++r) {
                    int m = bm + wm * 64 + i * 16 + lk * 4 + r;
                    outf[(size_t)m * DM + n] = acc[i][j][r] + bias;
                }
        } else {
            int mat = n >> 10, nl = n & 1023;
            int h_ = nl >> 6, d = nl & 63;
            const float* bp = (mat == 0) ? b0 : ((mat == 1) ? b1 : b2);
            float bias = bp[nl];
#pragma unroll
            for (int i = 0; i < 4; ++i) {
                int m0 = bm + wm * 64 + i * 16 + lk * 4;
                int b_ = m0 >> 11, s0 = m0 & (SLEN - 1);
                if (mat == 2) {
                    _Float16 v4[4];
#pragma unroll
                    for (int r = 0; r < 4; ++r) v4[r] = (_Float16)(acc[i][j][r] + bias);
                    *(ushort4*)&vtp[((size_t)(b_ * NH + h_) * DK + d) * SLEN + s0] = *(ushort4*)v4;
                } else {
                    _Float16* dst = (mat == 0) ? qf : kfp;
                    float sc = (mat == 0) ? QSCALE : 1.0f;
#pragma unroll
                    for (int r = 0; r < 4; ++r)
                        dst[((size_t)(b_ * NH + h_) * SLEN + s0 + r) * DK + d] =
                            (_Float16)((acc[i][j][r] + bias) * sc);
                }
            }
        }
    }
}

// ---------- swapped-operand 32x32 MFMA flash attention ----------
// qf,kf: f16 [bh][s][d] (q pre-scaled by log2e/8); vt: f16 [bh][d][s]
// out: f16 hi/lo [4096][1024].  Each lane owns ONE q-row (col of S^T / O^T).
__global__ __launch_bounds__(256, 2) void attn_mfma(
    const _Float16* __restrict__ qf, const _Float16* __restrict__ kf,
    const _Float16* __restrict__ vt,
    _Float16* __restrict__ aoh, _Float16* __restrict__ aol)
{
    __shared__ __align__(16) _Float16 Ks[2][64 * 64], Vs[2][64 * 64];
    const int tid = threadIdx.x, wid = tid >> 6, lane = tid & 63;
    const int ln = lane & 31, l5 = lane >> 5;
    // bijective XCD swizzle: 4 consecutive bh per XCD (KV L2-resident)
    const int phys = blockIdx.x;                    // 512 blocks
    const int virt = (phys & 7) * 64 + (phys >> 3);
    const int bh = virt >> 4, qb = virt & 15;
    const int qrow = qb * 128 + wid * 32 + ln;      // this lane's q row (s index)

    // Q fragments in registers: Q[qrow][16t + l5*8 + j]
    f16x8 qv[4];
#pragma unroll
    for (int t = 0; t < 4; ++t)
        qv[t] = *(const f16x8*)&qf[((size_t)bh * SLEN + qrow) * DK + t * 16 + l5 * 8];

    f32x16 O[2];
#pragma unroll
    for (int db = 0; db < 2; ++db)
#pragma unroll
        for (int r = 0; r < 16; ++r) O[db][r] = 0.f;
    float m_ = -1e30f, lp = 0.f;

    auto stage = [&](int b, int t) {
#pragma unroll
        for (int u = 0; u < 2; ++u) {
            int idx = u * 256 + tid, row = idx >> 3, c = (idx & 7) ^ (row & 7);
            int lo = (u * 256 + wid * 64) * 16;
            gload16(kf + ((size_t)bh * SLEN + t * 64 + row) * DK + c * 8,
                    (char*)&Ks[b][0] + lo);
            gload16(vt + ((size_t)(bh * DK + row)) * SLEN + t * 64 + c * 8,
                    (char*)&Vs[b][0] + lo);
        }
    };

    auto compute = [&](int b) {
        // S^T[k][q] = mfma(K-frag, Q-frag): lane holds 32 scores of its own q-row
        f32x16 S[2];
        __builtin_amdgcn_s_setprio(1);
#pragma unroll
        for (int kb = 0; kb < 2; ++kb) {
            f32x16 s;
#pragma unroll
            for (int r = 0; r < 16; ++r) s[r] = 0.f;
            int krow = kb * 32 + ln;
#pragma unroll
            for (int t = 0; t < 4; ++t) {
                int cd = (2 * t + l5) ^ (krow & 7);
                f16x8 ka = *(const f16x8*)&Ks[b][krow * 64 + cd * 8];
                s = MFMA32_F16(ka, qv[t], s);
            }
            S[kb] = s;
        }
        __builtin_amdgcn_s_setprio(0);

        // in-lane row max + single cross-lane combine
        float mx = S[0][0];
#pragma unroll
        for (int r = 1; r < 16; ++r) mx = fmaxf(mx, S[0][r]);
#pragma unroll
        for (int r = 0; r < 16; ++r) mx = fmaxf(mx, S[1][r]);
        mx = fmaxf(mx, __shfl_xor(mx, 32));

        bool need = mx > m_ + 8.0f;   // defer-max, log2 domain
        if (__any((int)need)) {
            float al = need ? exp2_hw(m_ - mx) : 1.0f;
            if (need) m_ = mx;
            lp *= al;
#pragma unroll
            for (int db = 0; db < 2; ++db)
#pragma unroll
                for (int r = 0; r < 16; ++r) O[db][r] *= al;
        }

        // exp2, sum, RNE-pack, permlane-exchange -> PV B-fragments in-register
        u32 pk_[2][8];
#pragma unroll
        for (int kb = 0; kb < 2; ++kb) {
#pragma unroll
            for (int i = 0; i < 8; ++i) {
                float p0 = exp2_hw(S[kb][2 * i] - m_);
                float p1 = exp2_hw(S[kb][2 * i + 1] - m_);
                lp += p0 + p1;
                pk_[kb][i] = pk2(p0, p1);
            }
            pl32swap(pk_[kb][0], pk_[kb][2]);
            pl32swap(pk_[kb][1], pk_[kb][3]);
            pl32swap(pk_[kb][4], pk_[kb][6]);
            pl32swap(pk_[kb][5], pk_[kb][7]);
        }

        // O^T[d][q] += mfma(V^T-frag, P-frag)
        __builtin_amdgcn_s_setprio(1);
#pragma unroll
        for (int kb = 0; kb < 2; ++kb)
#pragma unroll
            for (int t2 = 0; t2 < 2; ++t2) {
                union { u32 w[4]; f16x8 v; } pb;
#pragma unroll
                for (int w = 0; w < 4; ++w) pb.w[w] = pk_[kb][t2 * 4 + w];
#pragma unroll
                for (int db = 0; db < 2; ++db) {
                    int drow = db * 32 + ln;
                    int cd = (kb * 4 + t2 * 2 + l5) ^ (drow & 7);
                    f16x8 va = *(const f16x8*)&Vs[b][drow * 64 + cd * 8];
                    O[db] = MFMA32_F16(va, pb.v, O[db]);
                }
            }
        __builtin_amdgcn_s_setprio(0);
    };

    int buf = 0;
    stage(0, 0);
    VMCNT0(); BAR();
    for (int t = 0; t < SLEN / 64 - 1; ++t) {
        stage(buf ^ 1, t + 1);
        compute(buf);
        VMCNT0(); BAR();
        buf ^= 1;
    }
    compute(buf);

    // epilogue: combine partner l, normalize, f16 hi/lo split, 8B stores
    lp += __shfl_xor(lp, 32);
    float inv = 1.0f / lp;
    const int b_ = bh >> 4, h_ = bh & 15;
    size_t rowbase = ((size_t)(b_ * SLEN + qrow)) * DM + h_ * 64;
#pragma unroll
    for (int db = 0; db < 2; ++db)
#pragma unroll
        for (int u = 0; u < 4; ++u) {
            int dbase = 8 * u + 4 * l5 + 32 * db;
            _Float16 h4[4], l4[4];
#pragma unroll
            for (int j = 0; j < 4; ++j) {
                float v = O[db][4 * u + j] * inv;
                h4[j] = (_Float16)v;
                l4[j] = (_Float16)(v - (float)h4[j]);
            }
            *(ushort4*)&aoh[rowbase + dbase] = *(ushort4*)h4;
            *(ushort4*)&aol[rowbase + dbase] = *(ushort4*)l4;
        }
}

extern "C" void kernel_launch(void* const* d_in, const int* in_sizes, int n_in,
                              void* d_out, int out_size, void* d_ws, size_t ws_size,
                              hipStream_t stream) {
    const float* x  = (const float*)d_in[0];
    const float* Wq = (const float*)d_in[1];
    const float* bq = (const float*)d_in[2];
    const float* Wk = (const float*)d_in[3];
    const float* bk = (const float*)d_in[4];
    const float* Wv = (const float*)d_in[5];
    const float* bv = (const float*)d_in[6];
    const float* Wo = (const float*)d_in[7];
    const float* bo = (const float*)d_in[8];
    float* out = (float*)d_out;

    if (ws_size < (size_t)48 * 1024 * 1024) return;
    char* W = (char*)d_ws;
    _Float16* xh   = (_Float16*)(W);                       // 8MB, dead after QKV
    _Float16* xl   = (_Float16*)(W + ((size_t)8  << 20));  // 8MB, dead after QKV
    _Float16* wqkv = (_Float16*)(W + ((size_t)16 << 20));  // 6MB Wqkv^T f16
    _Float16* wo   = (_Float16*)(W + ((size_t)22 << 20));  // 2MB Wo^T f16
    _Float16* qf   = (_Float16*)(W + ((size_t)24 << 20));  // 8MB
    _Float16* kf   = (_Float16*)(W + ((size_t)32 << 20));  // 8MB
    _Float16* vt   = (_Float16*)(W + ((size_t)40 << 20));  // 8MB (V transposed)
    _Float16* aoh  = xh;                                   // reuse
    _Float16* aol  = xl;                                   // reuse

    cvt_x<<<dim3(MROWS * DM / 1024), dim3(256), 0, stream>>>(x, xh, xl);
    cvt_w4<<<dim3(16, 16, 4), dim3(256), 0, stream>>>(Wq, Wk, Wv, Wo, wqkv, wo);

    gemm_f16<1><<<dim3(32, 24), dim3(256), 0, stream>>>(
        (const u16*)xh, (const u16*)xl, (const u16*)wqkv,
        bq, bk, bv, nullptr, qf, kf, vt);

    attn_mfma<<<dim3(512), dim3(256), 0, stream>>>(qf, kf, vt, aoh, aol);

    gemm_f16<0><<<dim3(32, 8), dim3(256), 0, stream>>>(
        (const u16*)aoh, (const u16*)aol, (const u16*)wo,
        bo, nullptr, nullptr, out, nullptr, nullptr, nullptr);
}

// Round 7
// 157.569 us; speedup vs baseline: 7.5712x; 1.1111x over previous
//
#include <hip/hip_runtime.h>
#include <math.h>

#define DM    1024
#define NH    16
#define DK    64
#define SLEN  2048
#define NB    2
#define MROWS (NB*SLEN)   // 4096
#define QSCALE 0.1803368801111204f   // (1/8) * log2(e)

typedef unsigned short u16;
typedef unsigned int   u32;
typedef short  s16x8 __attribute__((ext_vector_type(8)));
typedef _Float16 f16x8 __attribute__((ext_vector_type(8)));
typedef float  f32x4  __attribute__((ext_vector_type(4)));
typedef float  f32x16 __attribute__((ext_vector_type(16)));

#define MFMA_F16(a,b,c)   __builtin_amdgcn_mfma_f32_16x16x32_f16(a,b,c,0,0,0)
#define MFMA32_F16(a,b,c) __builtin_amdgcn_mfma_f32_32x32x16_f16(a,b,c,0,0,0)

__device__ __forceinline__ void gload16(const void* g, void* l) {
    __builtin_amdgcn_global_load_lds((const __attribute__((address_space(1))) void*)g,
                                     (__attribute__((address_space(3))) void*)l, 16, 0, 0);
}
__device__ __forceinline__ f16x8 as_h(s16x8 v) {
    union { s16x8 s; f16x8 h; } u; u.s = v; return u.h;
}
__device__ __forceinline__ float exp2_hw(float x) {
    float r; asm("v_exp_f32 %0, %1" : "=v"(r) : "v"(x)); return r;
}
__device__ __forceinline__ u32 pk2(float a, float b) {   // RNE pack to half2
    union { _Float16 h[2]; u32 u; } x;
    x.h[0] = (_Float16)a; x.h[1] = (_Float16)b;
    return x.u;
}
__device__ __forceinline__ void pl32swap(u32& a, u32& b) {
    asm volatile("v_permlane32_swap_b32 %0, %1" : "+v"(a), "+v"(b));
}
#define VMCNT0() asm volatile("s_waitcnt vmcnt(0)" ::: "memory")
#define BAR()    __builtin_amdgcn_s_barrier()

// ---------- x (f32) -> hi/lo f16 split ----------
__global__ __launch_bounds__(256) void cvt_x(const float* __restrict__ in,
                                             _Float16* __restrict__ h, _Float16* __restrict__ l) {
    int i = (blockIdx.x * 256 + threadIdx.x) * 4;
    float4 v = *(const float4*)&in[i];
    float vv[4] = {v.x, v.y, v.z, v.w};
    _Float16 hv[4], lv[4];
#pragma unroll
    for (int j = 0; j < 4; ++j) {
        hv[j] = (_Float16)vv[j];
        lv[j] = (_Float16)(vv[j] - (float)hv[j]);
    }
    *(ushort4*)&h[i] = *(ushort4*)hv;
    *(ushort4*)&l[i] = *(ushort4*)lv;
}

// ---------- all four W (f32 [k][n]) -> W^T f16 [n][k], one launch ----------
__global__ __launch_bounds__(256) void cvt_w4(
    const float* __restrict__ Wq, const float* __restrict__ Wk,
    const float* __restrict__ Wv, const float* __restrict__ Wo,
    _Float16* __restrict__ wqkv, _Float16* __restrict__ wo) {
    __shared__ _Float16 ts[64][72];
    const int z = blockIdx.z;
    const float* W = (z == 0) ? Wq : (z == 1) ? Wk : (z == 2) ? Wv : Wo;
    _Float16* dst = (z < 3) ? (wqkv + (size_t)z * DM * DM) : wo;
    int k0 = blockIdx.x * 64, n0 = blockIdx.y * 64;
    int t = threadIdx.x, kr = t >> 4, c4 = (t & 15) * 4;
#pragma unroll
    for (int u = 0; u < 4; ++u) {
        int k = kr + u * 16;
        float4 v = *(const float4*)&W[(size_t)(k0 + k) * DM + n0 + c4];
        float vv[4] = {v.x, v.y, v.z, v.w};
#pragma unroll
        for (int j = 0; j < 4; ++j) ts[c4 + j][k] = (_Float16)vv[j];
    }
    __syncthreads();
#pragma unroll
    for (int u = 0; u < 4; ++u) {
        int n = kr + u * 16;
        _Float16 hv[4];
#pragma unroll
        for (int j = 0; j < 4; ++j) hv[j] = ts[n][c4 + j];
        *(ushort4*)&dst[(size_t)(n0 + n) * DM + k0 + c4] = *(ushort4*)hv;
    }
}

// ---------- f16 MFMA GEMM, 2-buffer depth-1 (R4-verified schedule) ----------
// EPI 1: 2-pass A (hi+lo), qkv epilogue (q scaled, v transposed).
// EPI 0: 1-pass A, f32 out + bias.
template<int EPI>
__global__ __launch_bounds__(256) void gemm_f16(
    const u16* __restrict__ Ah, const u16* __restrict__ Al,
    const u16* __restrict__ Bt,
    const float* __restrict__ b0, const float* __restrict__ b1, const float* __restrict__ b2,
    float* __restrict__ outf, _Float16* __restrict__ qf,
    _Float16* __restrict__ kfp, _Float16* __restrict__ vtp)
{
    __shared__ __align__(16) u16 sAh[2][4096];
    __shared__ __align__(16) u16 sAl[EPI ? 2 : 1][EPI ? 4096 : 4];
    __shared__ __align__(16) u16 sB[2][4096];
    const int tid = threadIdx.x, wid = tid >> 6, lane = tid & 63;
    const int lq = lane & 15, lk = lane >> 4;
    const int wm = wid >> 1, wn = wid & 1;
    const int bm = blockIdx.x * 128, bn = blockIdx.y * 128;

    const f32x4 fz = {0.f, 0.f, 0.f, 0.f};
    f32x4 acc[4][4];
#pragma unroll
    for (int i = 0; i < 4; ++i)
#pragma unroll
        for (int j = 0; j < 4; ++j) acc[i][j] = fz;

    auto stage = [&](int b, int k0) {
#pragma unroll
        for (int u = 0; u < 2; ++u) {
            int idx = u * 256 + tid, row = idx >> 2, c = (idx & 3) ^ ((row >> 1) & 3);
            size_t ga = (size_t)(bm + row) * DM + k0 + c * 8;
            size_t gb = (size_t)(bn + row) * DM + k0 + c * 8;
            int lo = (u * 256 + wid * 64) * 16;
            gload16(Ah + ga, (char*)&sAh[b][0] + lo);
            if constexpr (EPI == 1) gload16(Al + ga, (char*)&sAl[b][0] + lo);
            gload16(Bt + gb, (char*)&sB[b][0] + lo);
        }
    };
    auto compute = [&](int b) {
        s16x8 avh[4], avl[4], bv[4];
#pragma unroll
        for (int i = 0; i < 4; ++i) {
            int row = wm * 64 + i * 16 + lq;
            int off = row * 32 + ((lk ^ ((row >> 1) & 3)) << 3);
            avh[i] = *(const s16x8*)&sAh[b][off];
            if constexpr (EPI == 1) avl[i] = *(const s16x8*)&sAl[b][off];
        }
#pragma unroll
        for (int j = 0; j < 4; ++j) {
            int row = wn * 64 + j * 16 + lq;
            int off = row * 32 + ((lk ^ ((row >> 1) & 3)) << 3);
            bv[j] = *(const s16x8*)&sB[b][off];
        }
        __builtin_amdgcn_s_setprio(1);
#pragma unroll
        for (int i = 0; i < 4; ++i)
#pragma unroll
            for (int j = 0; j < 4; ++j) {
                acc[i][j] = MFMA_F16(as_h(avh[i]), as_h(bv[j]), acc[i][j]);
                if constexpr (EPI == 1)
                    acc[i][j] = MFMA_F16(as_h(avl[i]), as_h(bv[j]), acc[i][j]);
            }
        __builtin_amdgcn_s_setprio(0);
    };

    int buf = 0;
    stage(0, 0);
    VMCNT0(); BAR();
    for (int t = 0; t < 31; ++t) {
        stage(buf ^ 1, (t + 1) * 32);
        compute(buf);
        VMCNT0(); BAR();
        buf ^= 1;
    }
    compute(buf);

    // epilogue
#pragma unroll
    for (int j = 0; j < 4; ++j) {
        int n = bn + wn * 64 + j * 16 + lq;
        if constexpr (EPI == 0) {
            float bias = b0[n];
#pragma unroll
            for (int i = 0; i < 4; ++i)
#pragma unroll
                for (int r = 0; r < 4; ++r) {
                    int m = bm + wm * 64 + i * 16 + lk * 4 + r;
                    outf[(size_t)m * DM + n] = acc[i][j][r] + bias;
                }
        } else {
            int mat = n >> 10, nl = n & 1023;
            int h_ = nl >> 6, d = nl & 63;
            const float* bp = (mat == 0) ? b0 : ((mat == 1) ? b1 : b2);
            float bias = bp[nl];
#pragma unroll
            for (int i = 0; i < 4; ++i) {
                int m0 = bm + wm * 64 + i * 16 + lk * 4;
                int b_ = m0 >> 11, s0 = m0 & (SLEN - 1);
                if (mat == 2) {
                    _Float16 v4[4];
#pragma unroll
                    for (int r = 0; r < 4; ++r) v4[r] = (_Float16)(acc[i][j][r] + bias);
                    *(ushort4*)&vtp[((size_t)(b_ * NH + h_) * DK + d) * SLEN + s0] = *(ushort4*)v4;
                } else {
                    _Float16* dst = (mat == 0) ? qf : kfp;
                    float sc = (mat == 0) ? QSCALE : 1.0f;
#pragma unroll
                    for (int r = 0; r < 4; ++r)
                        dst[((size_t)(b_ * NH + h_) * SLEN + s0 + r) * DK + d] =
                            (_Float16)((acc[i][j][r] + bias) * sc);
                }
            }
        }
    }
}

// ---------- swapped-operand 32x32 MFMA flash attention (R4-verified schedule) ----
// qf,kf: f16 [bh][s][d] (q pre-scaled by log2e/8); vt: f16 [bh][d][s]
// out: f16 [4096][1024].  Each lane owns ONE q-row (col of S^T / O^T).
__global__ __launch_bounds__(256, 2) void attn_mfma(
    const _Float16* __restrict__ qf, const _Float16* __restrict__ kf,
    const _Float16* __restrict__ vt, _Float16* __restrict__ aoh)
{
    __shared__ __align__(16) _Float16 Ks[2][64 * 64], Vs[2][64 * 64];
    const int tid = threadIdx.x, wid = tid >> 6, lane = tid & 63;
    const int ln = lane & 31, l5 = lane >> 5;
    // bijective XCD swizzle: 4 consecutive bh per XCD (KV L2-resident)
    const int phys = blockIdx.x;                    // 512 blocks
    const int virt = (phys & 7) * 64 + (phys >> 3);
    const int bh = virt >> 4, qb = virt & 15;
    const int qrow = qb * 128 + wid * 32 + ln;      // this lane's q row (s index)

    // Q fragments in registers: Q[qrow][16t + l5*8 + j]
    f16x8 qv[4];
#pragma unroll
    for (int t = 0; t < 4; ++t)
        qv[t] = *(const f16x8*)&qf[((size_t)bh * SLEN + qrow) * DK + t * 16 + l5 * 8];

    f32x16 O[2];
#pragma unroll
    for (int db = 0; db < 2; ++db)
#pragma unroll
        for (int r = 0; r < 16; ++r) O[db][r] = 0.f;
    float m_ = -1e30f, lp = 0.f;

    auto stage = [&](int b, int t) {
#pragma unroll
        for (int u = 0; u < 2; ++u) {
            int idx = u * 256 + tid, row = idx >> 3, c = (idx & 7) ^ (row & 7);
            int lo = (u * 256 + wid * 64) * 16;
            gload16(kf + ((size_t)bh * SLEN + t * 64 + row) * DK + c * 8,
                    (char*)&Ks[b][0] + lo);
            gload16(vt + ((size_t)(bh * DK + row)) * SLEN + t * 64 + c * 8,
                    (char*)&Vs[b][0] + lo);
        }
    };

    auto compute = [&](int b) {
        // S^T[k][q] = mfma(K-frag, Q-frag): lane holds 32 scores of its own q-row
        f32x16 S[2];
        __builtin_amdgcn_s_setprio(1);
#pragma unroll
        for (int kb = 0; kb < 2; ++kb) {
            f32x16 s;
#pragma unroll
            for (int r = 0; r < 16; ++r) s[r] = 0.f;
            int krow = kb * 32 + ln;
#pragma unroll
            for (int t = 0; t < 4; ++t) {
                int cd = (2 * t + l5) ^ (krow & 7);
                f16x8 ka = *(const f16x8*)&Ks[b][krow * 64 + cd * 8];
                s = MFMA32_F16(ka, qv[t], s);
            }
            S[kb] = s;
        }
        __builtin_amdgcn_s_setprio(0);

        // in-lane row max + single cross-lane combine
        float mx = S[0][0];
#pragma unroll
        for (int r = 1; r < 16; ++r) mx = fmaxf(mx, S[0][r]);
#pragma unroll
        for (int r = 0; r < 16; ++r) mx = fmaxf(mx, S[1][r]);
        mx = fmaxf(mx, __shfl_xor(mx, 32));

        bool need = mx > m_ + 8.0f;   // defer-max, log2 domain
        if (__any((int)need)) {
            float al = need ? exp2_hw(m_ - mx) : 1.0f;
            if (need) m_ = mx;
            lp *= al;
#pragma unroll
            for (int db = 0; db < 2; ++db)
#pragma unroll
                for (int r = 0; r < 16; ++r) O[db][r] *= al;
        }

        // exp2, sum, RNE-pack, permlane-exchange -> PV B-fragments in-register
        u32 pk_[2][8];
#pragma unroll
        for (int kb = 0; kb < 2; ++kb) {
#pragma unroll
            for (int i = 0; i < 8; ++i) {
                float p0 = exp2_hw(S[kb][2 * i] - m_);
                float p1 = exp2_hw(S[kb][2 * i + 1] - m_);
                lp += p0 + p1;
                pk_[kb][i] = pk2(p0, p1);
            }
            pl32swap(pk_[kb][0], pk_[kb][2]);
            pl32swap(pk_[kb][1], pk_[kb][3]);
            pl32swap(pk_[kb][4], pk_[kb][6]);
            pl32swap(pk_[kb][5], pk_[kb][7]);
        }

        // O^T[d][q] += mfma(V^T-frag, P-frag)
        __builtin_amdgcn_s_setprio(1);
#pragma unroll
        for (int kb = 0; kb < 2; ++kb)
#pragma unroll
            for (int t2 = 0; t2 < 2; ++t2) {
                union { u32 w[4]; f16x8 v; } pb;
#pragma unroll
                for (int w = 0; w < 4; ++w) pb.w[w] = pk_[kb][t2 * 4 + w];
#pragma unroll
                for (int db = 0; db < 2; ++db) {
                    int drow = db * 32 + ln;
                    int cd = (kb * 4 + t2 * 2 + l5) ^ (drow & 7);
                    f16x8 va = *(const f16x8*)&Vs[b][drow * 64 + cd * 8];
                    O[db] = MFMA32_F16(va, pb.v, O[db]);
                }
            }
        __builtin_amdgcn_s_setprio(0);
    };

    int buf = 0;
    stage(0, 0);
    VMCNT0(); BAR();
    for (int t = 0; t < SLEN / 64 - 1; ++t) {
        stage(buf ^ 1, t + 1);
        compute(buf);
        VMCNT0(); BAR();
        buf ^= 1;
    }
    compute(buf);

    // epilogue: combine partner l, normalize, f16 out, 8B stores
    lp += __shfl_xor(lp, 32);
    float inv = 1.0f / lp;
    const int b_ = bh >> 4, h_ = bh & 15;
    size_t rowbase = ((size_t)(b_ * SLEN + qrow)) * DM + h_ * 64;
#pragma unroll
    for (int db = 0; db < 2; ++db)
#pragma unroll
        for (int u = 0; u < 4; ++u) {
            int dbase = 8 * u + 4 * l5 + 32 * db;
            _Float16 h4[4];
#pragma unroll
            for (int j = 0; j < 4; ++j) h4[j] = (_Float16)(O[db][4 * u + j] * inv);
            *(ushort4*)&aoh[rowbase + dbase] = *(ushort4*)h4;
        }
}

extern "C" void kernel_launch(void* const* d_in, const int* in_sizes, int n_in,
                              void* d_out, int out_size, void* d_ws, size_t ws_size,
                              hipStream_t stream) {
    const float* x  = (const float*)d_in[0];
    const float* Wq = (const float*)d_in[1];
    const float* bq = (const float*)d_in[2];
    const float* Wk = (const float*)d_in[3];
    const float* bk = (const float*)d_in[4];
    const float* Wv = (const float*)d_in[5];
    const float* bv = (const float*)d_in[6];
    const float* Wo = (const float*)d_in[7];
    const float* bo = (const float*)d_in[8];
    float* out = (float*)d_out;

    if (ws_size < (size_t)48 * 1024 * 1024) return;
    char* W = (char*)d_ws;
    _Float16* xh   = (_Float16*)(W);                       // 8MB, dead after QKV
    _Float16* xl   = (_Float16*)(W + ((size_t)8  << 20));  // 8MB, dead after QKV
    _Float16* wqkv = (_Float16*)(W + ((size_t)16 << 20));  // 6MB Wqkv^T f16
    _Float16* wo   = (_Float16*)(W + ((size_t)22 << 20));  // 2MB Wo^T f16
    _Float16* qf   = (_Float16*)(W + ((size_t)24 << 20));  // 8MB
    _Float16* kf   = (_Float16*)(W + ((size_t)32 << 20));  // 8MB
    _Float16* vt   = (_Float16*)(W + ((size_t)40 << 20));  // 8MB (V transposed)
    _Float16* aoh  = xh;                                   // reuse xh region

    cvt_x<<<dim3(MROWS * DM / 1024), dim3(256), 0, stream>>>(x, xh, xl);
    cvt_w4<<<dim3(16, 16, 4), dim3(256), 0, stream>>>(Wq, Wk, Wv, Wo, wqkv, wo);

    gemm_f16<1><<<dim3(32, 24), dim3(256), 0, stream>>>(
        (const u16*)xh, (const u16*)xl, (const u16*)wqkv,
        bq, bk, bv, nullptr, qf, kf, vt);

    attn_mfma<<<dim3(512), dim3(256), 0, stream>>>(qf, kf, vt, aoh);

    gemm_f16<0><<<dim3(32, 8), dim3(256), 0, stream>>>(
        (const u16*)aoh, nullptr, (const u16*)wo,
        bo, nullptr, nullptr, out, nullptr, nullptr, nullptr);
}